// Round 8
// baseline (361.814 us; speedup 1.0000x reference)
//
#include <hip/hip_runtime.h>
#include <cstdint>
#include <cstddef>

#define BB 16
#define PP 19248
#define NOBJ 32
#define NCLS 81
#define POS_TH 0.5f
#define NEG_TH 0.4f
#define VAR0 0.1f
#define VAR1 0.2f
#define NEGPOS 3

#define MTB 256
#define NMB ((PP + MTB - 1) / MTB)      // 76
#define KTB 256                          // 4 waves/block, 64 rows per wave
#define NKB ((PP + KTB - 1) / KTB)      // 76 blocks-x per batch; block covers 256 rows
#define ST 1024

// ---------------- match A: per-prior best gt (no shfl, no atomics) ----------------
__global__ __launch_bounds__(MTB) void k_match_prior(const float* __restrict__ priors,
                                                     const float* __restrict__ gt_boxes,
                                                     float* __restrict__ bto,
                                                     int* __restrict__ bti) {
    const int b = blockIdx.y;
    const int p = blockIdx.x * MTB + threadIdx.x;
    __shared__ float4 sg[NOBJ];
    if (threadIdx.x < NOBJ) sg[threadIdx.x] = ((const float4*)gt_boxes)[b * NOBJ + threadIdx.x];
    __syncthreads();
    if (p >= PP) return;

    float4 pr = ((const float4*)priors)[p];
    float hw = pr.z / 2.0f, hh = pr.w / 2.0f;
    float px1 = pr.x - hw, py1 = pr.y - hh, px2 = pr.x + hw, py2 = pr.y + hh;
    float parea = (px2 - px1) * (py2 - py1);

    float best = -1.0f;
    int bn = 0;
#pragma unroll 4
    for (int n = 0; n < NOBJ; ++n) {
        float4 g = sg[n];
        float iou;
        {
#pragma clang fp contract(off)
            float ix1 = fmaxf(g.x, px1), iy1 = fmaxf(g.y, py1);
            float ix2 = fminf(g.z, px2), iy2 = fminf(g.w, py2);
            float iw = fmaxf(ix2 - ix1, 0.0f), ih = fmaxf(iy2 - iy1, 0.0f);
            float inter = iw * ih;
            float garea = (g.z - g.x) * (g.w - g.y);
            iou = inter / (garea + parea - inter);
        }
        if (iou > best) { best = iou; bn = n; }
    }
    bto[(size_t)b * PP + p] = best;
    bti[(size_t)b * PP + p] = bn;
}

// ---------------- match B: per-gt best prior (one wave per (b,n), zero atomics) ----------------
__global__ __launch_bounds__(256) void k_match_gt(const float* __restrict__ priors,
                                                  const float* __restrict__ gt_boxes,
                                                  unsigned long long* __restrict__ gkey) {
    const int w = (blockIdx.x * 256 + threadIdx.x) >> 6;
    if (w >= BB * NOBJ) return;
    const int b = w >> 5, n = w & 31;
    const int lane = threadIdx.x & 63;

    const float* g = gt_boxes + (size_t)(b * NOBJ + n) * 4;
    const float gx1 = g[0], gy1 = g[1], gx2 = g[2], gy2 = g[3];
    const float garea = (gx2 - gx1) * (gy2 - gy1);

    unsigned long long best = 0ull;
    for (int p = lane; p < PP; p += 64) {
        float4 pr = ((const float4*)priors)[p];
        float hw = pr.z / 2.0f, hh = pr.w / 2.0f;
        float px1 = pr.x - hw, py1 = pr.y - hh, px2 = pr.x + hw, py2 = pr.y + hh;
        float parea = (px2 - px1) * (py2 - py1);
        float iou;
        {
#pragma clang fp contract(off)
            float ix1 = fmaxf(gx1, px1), iy1 = fmaxf(gy1, py1);
            float ix2 = fminf(gx2, px2), iy2 = fminf(gy2, py2);
            float iw = fmaxf(ix2 - ix1, 0.0f), ih = fmaxf(iy2 - iy1, 0.0f);
            float inter = iw * ih;
            iou = inter / (garea + parea - inter);
        }
        unsigned long long key = (((unsigned long long)__float_as_uint(iou)) << 32) |
                                 (unsigned long long)(0xFFFFFFFFu - (unsigned)p);
        if (key > best) best = key;
    }
    for (int off = 1; off < 64; off <<= 1) {
        unsigned long long o = __shfl_xor(best, off, 64);
        if (o > best) best = o;
    }
    if (lane == 0) gkey[b * NOBJ + n] = best;   // plain store, no atomics
}

__device__ __forceinline__ float sl1(float d) {
    float ad = fabsf(d);
    return ad < 1.0f ? 0.5f * d * d : ad - 0.5f;
}

// ---------------- main: wave-per-row, no LDS staging, no barriers in hot path ----------------
// Lane c holds row[c] (c<64) and row[64+c] (c<17). Coalesced loads, butterfly
// exp-sum, everything else via ballot/shfl register games. Zero atomics.
__global__ __launch_bounds__(KTB) void k_main(const float* __restrict__ loc_data,
                                              const float* __restrict__ conf_data,
                                              const float* __restrict__ priors,
                                              const float* __restrict__ gt_boxes,
                                              const int* __restrict__ gt_labels,
                                              const float* __restrict__ bto,
                                              const int* __restrict__ bti,
                                              const unsigned long long* __restrict__ gkey,
                                              float* __restrict__ mine,
                                              float* __restrict__ p_ll,
                                              float* __restrict__ p_lc,
                                              int* __restrict__ p_np) {
    const int b = blockIdx.y;
    const int tid = threadIdx.x;
    const int wid = tid >> 6, lane = tid & 63;
    const int base = blockIdx.x * KTB + wid * 64;
    const int nrows = min(64, PP - base);   // may be <= 0 for tail waves

    // preload per-gt state into lanes 0..31 (wave-resident for the whole span)
    unsigned pstar = 0xFFFFFFFFu;
    int lab = 0;
    if (lane < NOBJ) {
        unsigned long long key = gkey[b * NOBJ + lane];
        pstar = 0xFFFFFFFFu - (unsigned)(key & 0xFFFFFFFFull);
        lab = gt_labels[b * NOBJ + lane];
    }

    float a_ll = 0.0f, a_lc = 0.0f;
    int a_np = 0;
    float mval = 0.0f;

    if (nrows > 0) {
        const float* row0 = conf_data + ((size_t)b * PP + base) * NCLS;
        // prefetch row 0
        float nv1 = row0[lane];
        float nv2 = (lane < NCLS - 64) ? row0[64 + lane] : -1e30f;

        for (int j = 0; j < nrows; ++j) {
            const int r = base + j;
            float v1 = nv1, v2 = nv2;
            if (j + 1 < nrows) {   // prefetch next row while we crunch this one
                const float* rn = row0 + (size_t)(j + 1) * NCLS;
                nv1 = rn[lane];
                nv2 = (lane < NCLS - 64) ? rn[64 + lane] : -1e30f;
            }

            float e = __expf(v1) + __expf(v2);   // exp(-1e30) = 0 for pad lanes
            e += __shfl_xor(e, 1, 64);
            e += __shfl_xor(e, 2, 64);
            e += __shfl_xor(e, 4, 64);
            e += __shfl_xor(e, 8, 64);
            e += __shfl_xor(e, 16, 64);
            e += __shfl_xor(e, 32, 64);
            const float lse = __logf(e);

            float ov = bto[(size_t)b * PP + r];   // same-addr broadcast load
            int ti = bti[(size_t)b * PP + r];
            unsigned long long ball = __ballot(pstar == (unsigned)r);
            if (ball) {                            // forced prior: last n wins
                ti = 63 - __builtin_clzll(ball);
                ov = 2.0f;
            }
            int conf_c = __shfl(lab, ti, 64) + 1;
            if (ov < POS_TH) conf_c = -1;
            if (ov < NEG_TH) conf_c = 0;
            const int ct = conf_c > 0 ? conf_c : 0;
            const float vct = (ct < 64) ? __shfl(v1, ct, 64) : __shfl(v2, ct - 64, 64);
            const float nll = lse - vct;

            if (conf_c > 0) {                      // wave-uniform branch, rare
                float4 gbox = ((const float4*)gt_boxes)[b * NOBJ + ti];
                float4 pr = ((const float4*)priors)[r];
                float mcx = (gbox.x + gbox.z) / 2.0f, mcy = (gbox.y + gbox.w) / 2.0f;
                float mw = gbox.z - gbox.x, mh = gbox.w - gbox.y;
                float t0 = (mcx - pr.x) / (VAR0 * pr.z);
                float t1 = (mcy - pr.y) / (VAR0 * pr.w);
                float t2 = logf(mw / pr.z) / VAR1;
                float t3 = logf(mh / pr.w) / VAR1;
                float4 ld = ((const float4*)loc_data)[(size_t)b * PP + r];
                a_ll += sl1(ld.x - t0) + sl1(ld.y - t1) + sl1(ld.z - t2) + sl1(ld.w - t3);
                a_lc += nll;
                a_np += 1;
            }
            mval = (lane == j) ? ((conf_c == 0) ? nll : 0.0f) : mval;
        }
        if (lane < nrows) mine[(size_t)b * PP + base + lane] = mval;   // one coalesced store
    }

    // per-block slot store (a_* are wave-uniform; take lane 0 of each wave)
    __shared__ float sll[4], slc[4];
    __shared__ int snp[4];
    if (lane == 0) { sll[wid] = a_ll; slc[wid] = a_lc; snp[wid] = a_np; }
    __syncthreads();
    if (tid == 0) {
        p_ll[b * NKB + blockIdx.x] = sll[0] + sll[1] + sll[2] + sll[3];
        p_lc[b * NKB + blockIdx.x] = slc[0] + slc[1] + slc[2] + slc[3];
        p_np[b * NKB + blockIdx.x] = snp[0] + snp[1] + snp[2] + snp[3];
    }
}

// ---------------- select: partial-slot reduce + ballot radix top-k + fused finalize ----------------
__global__ __launch_bounds__(ST) void k_select(const float* __restrict__ mine,
                                               const float* __restrict__ p_ll,
                                               const float* __restrict__ p_lc,
                                               const int* __restrict__ p_np,
                                               float* __restrict__ acc,
                                               int* __restrict__ acc_np,
                                               unsigned* __restrict__ done,
                                               float* __restrict__ out) {
    const int b = blockIdx.x;
    const int tid = threadIdx.x;
    const int wid = tid >> 6, lane = tid & 63;
    constexpr int NW = ST / 64;

    float ll = 0.0f, lc = 0.0f;
    int np = 0;
    for (int i = tid; i < NKB; i += ST) {
        ll += p_ll[b * NKB + i];
        lc += p_lc[b * NKB + i];
        np += p_np[b * NKB + i];
    }
    for (int off = 32; off > 0; off >>= 1) {
        ll += __shfl_down(ll, off, 64);
        lc += __shfl_down(lc, off, 64);
        np += __shfl_down(np, off, 64);
    }
    __shared__ float rll[NW], rlc[NW];
    __shared__ int rnp[NW];
    __shared__ float s_ll, s_lc;
    __shared__ int s_np;
    if (lane == 0) { rll[wid] = ll; rlc[wid] = lc; rnp[wid] = np; }
    __syncthreads();
    if (tid == 0) {
        float a = 0.0f, c = 0.0f;
        int n = 0;
        for (int w = 0; w < NW; ++w) { a += rll[w]; c += rlc[w]; n += rnp[w]; }
        s_ll = a; s_lc = c; s_np = n;
    }
    __syncthreads();
    const int np_b = s_np;
    const int k = min(NEGPOS * np_b, PP - 1);
    float neg = 0.0f;

    const float* mv = mine + (size_t)b * PP;
    if (k > 0) {
        __shared__ unsigned swh[NW * 16];
        __shared__ unsigned stot[16];
        __shared__ unsigned s_prefix;
        __shared__ int s_rem;
        __shared__ float s_neg;
        if (tid == 0) { s_prefix = 0u; s_rem = k; }
        __syncthreads();

        for (int pass = 0; pass < 8; ++pass) {
            const int shift = 28 - 4 * pass;
            const unsigned hm = (pass == 0) ? 0u : (0xFFFFFFFFu << (shift + 4));
            const unsigned prefix = s_prefix;

            unsigned cnt[16];
#pragma unroll
            for (int v = 0; v < 16; ++v) cnt[v] = 0u;

            for (int i = tid; i < PP; i += ST) {
                unsigned bits = __float_as_uint(mv[i]);
                unsigned key = ((bits & hm) == prefix) ? ((bits >> shift) & 15u) : 16u;
                if (__any(key != 16u)) {
#pragma unroll
                    for (int v = 0; v < 16; ++v)
                        cnt[v] += (unsigned)__popcll(__ballot(key == (unsigned)v));
                }
            }
            if (lane == 0) {
#pragma unroll
                for (int v = 0; v < 16; ++v) swh[wid * 16 + v] = cnt[v];
            }
            __syncthreads();
            if (tid < 16) {
                unsigned tt = 0;
#pragma unroll
                for (int w = 0; w < NW; ++w) tt += swh[w * 16 + tid];
                stot[tid] = tt;
            }
            __syncthreads();
            if (tid == 0) {
                int rem = s_rem;
                unsigned cum = 0;
                int chosen = 0;
                for (int v = 15; v >= 0; --v) {
                    unsigned c = stot[v];
                    if (cum + c >= (unsigned)rem) { chosen = v; s_rem = rem - (int)cum; break; }
                    cum += c;
                }
                s_prefix = prefix | ((unsigned)chosen << shift);
            }
            __syncthreads();
        }

        const unsigned T = s_prefix;
        float sum = 0.0f;
        unsigned cnt = 0;
        for (int i = tid; i < PP; i += ST) {
            float v = mv[i];
            if (__float_as_uint(v) > T) { sum += v; cnt++; }
        }
        for (int off = 32; off > 0; off >>= 1) {
            sum += __shfl_down(sum, off, 64);
            cnt += __shfl_down(cnt, off, 64);
        }
        __shared__ float rs[NW];
        __shared__ unsigned rc[NW];
        if (lane == 0) { rs[wid] = sum; rc[wid] = cnt; }
        __syncthreads();
        if (tid == 0) {
            float S = 0.0f;
            int G = 0;
            for (int w = 0; w < NW; ++w) { S += rs[w]; G += (int)rc[w]; }
            s_neg = S + (float)(k - G) * __uint_as_float(T);
        }
        __syncthreads();
        neg = s_neg;
    }

    if (tid == 0) {
        atomicAdd(&acc[0], s_ll);
        atomicAdd(&acc[1], s_lc + neg);
        atomicAdd(acc_np, np_b);
        __threadfence();
        unsigned prev = atomicAdd(done, 1u);
        if (prev == BB - 1) {
            int tp = atomicAdd(acc_np, 0);
            float N = (float)max(tp, 1);
            float a0 = atomicAdd(&acc[0], 0.0f);
            float a1 = atomicAdd(&acc[1], 0.0f);
            out[0] = a0 / N;
            out[1] = a1 / N;
        }
    }
}

extern "C" void kernel_launch(void* const* d_in, const int* in_sizes, int n_in,
                              void* d_out, int out_size, void* d_ws, size_t ws_size,
                              hipStream_t stream) {
    const float* loc    = (const float*)d_in[0];
    const float* conf   = (const float*)d_in[1];
    const float* priors = (const float*)d_in[2];
    const float* gt     = (const float*)d_in[3];
    const int*   labels = (const int*)d_in[4];
    float* out = (float*)d_out;

    char* ws = (char*)d_ws;
    const size_t SZ_BP = (size_t)BB * PP * 4;        // 1,231,872 B
    const size_t SZ_SLOT = (size_t)BB * NKB * 4;     // 4,864 B
    // [0,8) acc | [8,12) acc_np | [12,16) done | [64,4160) gkey | arrays @4224
    float*    acc    = (float*)   (ws);
    int*      acc_np = (int*)     (ws + 8);
    unsigned* done   = (unsigned*)(ws + 12);
    unsigned long long* gkey = (unsigned long long*)(ws + 64);
    float* bto  = (float*)(ws + 4224);
    int*   bti  = (int*)  (ws + 4224 + SZ_BP);
    float* mine = (float*)(ws + 4224 + 2 * SZ_BP);
    float* p_ll = (float*)(ws + 4224 + 3 * SZ_BP);
    float* p_lc = (float*)(ws + 4224 + 3 * SZ_BP + SZ_SLOT);
    int*   p_np = (int*)  (ws + 4224 + 3 * SZ_BP + 2 * SZ_SLOT);

    (void)hipMemsetAsync(ws, 0, 64, stream);   // acc + acc_np + done only (gkey fully written)

    dim3 mg(NMB, BB);
    k_match_prior<<<mg, MTB, 0, stream>>>(priors, gt, bto, bti);

    k_match_gt<<<128, 256, 0, stream>>>(priors, gt, gkey);

    dim3 kg(NKB, BB);
    k_main<<<kg, KTB, 0, stream>>>(loc, conf, priors, gt, labels, bto, bti, gkey,
                                   mine, p_ll, p_lc, p_np);

    k_select<<<BB, ST, 0, stream>>>(mine, p_ll, p_lc, p_np, acc, acc_np, done, out);
}

// Round 9
// 284.570 us; speedup vs baseline: 1.2714x; 1.2714x over previous
//
#include <hip/hip_runtime.h>
#include <cstdint>
#include <cstddef>

#define BB 16
#define PP 19248
#define NOBJ 32
#define NCLS 81
#define POS_TH 0.5f
#define NEG_TH 0.4f
#define VAR0 0.1f
#define VAR1 0.2f
#define NEGPOS 3

#define MTB 256
#define NMB ((PP + MTB - 1) / MTB)      // 76
#define KTB 256                          // 4 waves/block, 64 rows per wave
#define NKB ((PP + KTB - 1) / KTB)      // 76
#define ST 1024
#define GTCH 8                           // chunks per (b,n) in k_match_gt
#define GTC 2406                         // priors per chunk (8*2406 = 19248)

// ---------------- match A: per-prior best gt (no shfl, no atomics) ----------------
__global__ __launch_bounds__(MTB) void k_match_prior(const float* __restrict__ priors,
                                                     const float* __restrict__ gt_boxes,
                                                     float* __restrict__ bto,
                                                     int* __restrict__ bti) {
    const int b = blockIdx.y;
    const int p = blockIdx.x * MTB + threadIdx.x;
    __shared__ float4 sg[NOBJ];
    if (threadIdx.x < NOBJ) sg[threadIdx.x] = ((const float4*)gt_boxes)[b * NOBJ + threadIdx.x];
    __syncthreads();
    if (p >= PP) return;

    float4 pr = ((const float4*)priors)[p];
    float hw = pr.z / 2.0f, hh = pr.w / 2.0f;
    float px1 = pr.x - hw, py1 = pr.y - hh, px2 = pr.x + hw, py2 = pr.y + hh;
    float parea = (px2 - px1) * (py2 - py1);

    float best = -1.0f;
    int bn = 0;
#pragma unroll 4
    for (int n = 0; n < NOBJ; ++n) {
        float4 g = sg[n];
        float iou;
        {
#pragma clang fp contract(off)
            float ix1 = fmaxf(g.x, px1), iy1 = fmaxf(g.y, py1);
            float ix2 = fminf(g.z, px2), iy2 = fminf(g.w, py2);
            float iw = fmaxf(ix2 - ix1, 0.0f), ih = fmaxf(iy2 - iy1, 0.0f);
            float inter = iw * ih;
            float garea = (g.z - g.x) * (g.w - g.y);
            iou = inter / (garea + parea - inter);
        }
        if (iou > best) { best = iou; bn = n; }
    }
    bto[(size_t)b * PP + p] = best;
    bti[(size_t)b * PP + p] = bn;
}

// ---------------- match B: per-gt best prior, 8-way chunked (4096 waves + atomicMax) ----------------
__global__ __launch_bounds__(256) void k_match_gt(const float* __restrict__ priors,
                                                  const float* __restrict__ gt_boxes,
                                                  unsigned long long* __restrict__ gkey) {
    const int w = (blockIdx.x * 256 + threadIdx.x) >> 6;   // 0..4095
    const int b = w >> 8;                 // 256 waves per batch
    const int rem = w & 255;
    const int n = rem >> 3, chunk = rem & 7;
    const int lane = threadIdx.x & 63;

    const float* g = gt_boxes + (size_t)(b * NOBJ + n) * 4;
    const float gx1 = g[0], gy1 = g[1], gx2 = g[2], gy2 = g[3];
    const float garea = (gx2 - gx1) * (gy2 - gy1);

    const int pbeg = chunk * GTC;
    const int pend = min(pbeg + GTC, PP);

    unsigned long long best = 0ull;
    for (int p = pbeg + lane; p < pend; p += 64) {
        float4 pr = ((const float4*)priors)[p];
        float hw = pr.z / 2.0f, hh = pr.w / 2.0f;
        float px1 = pr.x - hw, py1 = pr.y - hh, px2 = pr.x + hw, py2 = pr.y + hh;
        float parea = (px2 - px1) * (py2 - py1);
        float iou;
        {
#pragma clang fp contract(off)
            float ix1 = fmaxf(gx1, px1), iy1 = fmaxf(gy1, py1);
            float ix2 = fminf(gx2, px2), iy2 = fminf(gy2, py2);
            float iw = fmaxf(ix2 - ix1, 0.0f), ih = fmaxf(iy2 - iy1, 0.0f);
            float inter = iw * ih;
            iou = inter / (garea + parea - inter);
        }
        unsigned long long key = (((unsigned long long)__float_as_uint(iou)) << 32) |
                                 (unsigned long long)(0xFFFFFFFFu - (unsigned)p);
        if (key > best) best = key;
    }
    for (int off = 1; off < 64; off <<= 1) {
        unsigned long long o = __shfl_xor(best, off, 64);
        if (o > best) best = o;
    }
    if (lane == 0) atomicMax(&gkey[b * NOBJ + n], best);   // 8 atomics/address total
}

__device__ __forceinline__ float sl1(float d) {
    float ad = fabsf(d);
    return ad < 1.0f ? 0.5f * d * d : ad - 0.5f;
}

// ---------------- main: wave-per-row, no LDS staging, no barriers in hot path ----------------
__global__ __launch_bounds__(KTB) void k_main(const float* __restrict__ loc_data,
                                              const float* __restrict__ conf_data,
                                              const float* __restrict__ priors,
                                              const float* __restrict__ gt_boxes,
                                              const int* __restrict__ gt_labels,
                                              const float* __restrict__ bto,
                                              const int* __restrict__ bti,
                                              const unsigned long long* __restrict__ gkey,
                                              float* __restrict__ mine,
                                              float* __restrict__ p_ll,
                                              float* __restrict__ p_lc,
                                              int* __restrict__ p_np) {
    const int b = blockIdx.y;
    const int tid = threadIdx.x;
    const int wid = tid >> 6, lane = tid & 63;
    const int base = blockIdx.x * KTB + wid * 64;
    const int nrows = min(64, PP - base);

    unsigned pstar = 0xFFFFFFFFu;
    int lab = 0;
    if (lane < NOBJ) {
        unsigned long long key = gkey[b * NOBJ + lane];
        pstar = 0xFFFFFFFFu - (unsigned)(key & 0xFFFFFFFFull);
        lab = gt_labels[b * NOBJ + lane];
    }

    float a_ll = 0.0f, a_lc = 0.0f;
    int a_np = 0;
    float mval = 0.0f;

    if (nrows > 0) {
        const float* row0 = conf_data + ((size_t)b * PP + base) * NCLS;
        float nv1 = row0[lane];
        float nv2 = (lane < NCLS - 64) ? row0[64 + lane] : -1e30f;

        for (int j = 0; j < nrows; ++j) {
            const int r = base + j;
            float v1 = nv1, v2 = nv2;
            if (j + 1 < nrows) {
                const float* rn = row0 + (size_t)(j + 1) * NCLS;
                nv1 = rn[lane];
                nv2 = (lane < NCLS - 64) ? rn[64 + lane] : -1e30f;
            }

            float e = __expf(v1) + __expf(v2);
            e += __shfl_xor(e, 1, 64);
            e += __shfl_xor(e, 2, 64);
            e += __shfl_xor(e, 4, 64);
            e += __shfl_xor(e, 8, 64);
            e += __shfl_xor(e, 16, 64);
            e += __shfl_xor(e, 32, 64);
            const float lse = __logf(e);

            float ov = bto[(size_t)b * PP + r];
            int ti = bti[(size_t)b * PP + r];
            unsigned long long ball = __ballot(pstar == (unsigned)r);
            if (ball) {
                ti = 63 - __builtin_clzll(ball);
                ov = 2.0f;
            }
            int conf_c = __shfl(lab, ti, 64) + 1;
            if (ov < POS_TH) conf_c = -1;
            if (ov < NEG_TH) conf_c = 0;
            const int ct = conf_c > 0 ? conf_c : 0;
            const float vct = (ct < 64) ? __shfl(v1, ct, 64) : __shfl(v2, ct - 64, 64);
            const float nll = lse - vct;

            if (conf_c > 0) {
                float4 gbox = ((const float4*)gt_boxes)[b * NOBJ + ti];
                float4 pr = ((const float4*)priors)[r];
                float mcx = (gbox.x + gbox.z) / 2.0f, mcy = (gbox.y + gbox.w) / 2.0f;
                float mw = gbox.z - gbox.x, mh = gbox.w - gbox.y;
                float t0 = (mcx - pr.x) / (VAR0 * pr.z);
                float t1 = (mcy - pr.y) / (VAR0 * pr.w);
                float t2 = logf(mw / pr.z) / VAR1;
                float t3 = logf(mh / pr.w) / VAR1;
                float4 ld = ((const float4*)loc_data)[(size_t)b * PP + r];
                a_ll += sl1(ld.x - t0) + sl1(ld.y - t1) + sl1(ld.z - t2) + sl1(ld.w - t3);
                a_lc += nll;
                a_np += 1;
            }
            mval = (lane == j) ? ((conf_c == 0) ? nll : 0.0f) : mval;
        }
        if (lane < nrows) mine[(size_t)b * PP + base + lane] = mval;
    }

    __shared__ float sll[4], slc[4];
    __shared__ int snp[4];
    if (lane == 0) { sll[wid] = a_ll; slc[wid] = a_lc; snp[wid] = a_np; }
    __syncthreads();
    if (tid == 0) {
        p_ll[b * NKB + blockIdx.x] = sll[0] + sll[1] + sll[2] + sll[3];
        p_lc[b * NKB + blockIdx.x] = slc[0] + slc[1] + slc[2] + slc[3];
        p_np[b * NKB + blockIdx.x] = snp[0] + snp[1] + snp[2] + snp[3];
    }
}

// ---------------- select: partial-slot reduce + ballot radix top-k + fused finalize ----------------
__global__ __launch_bounds__(ST) void k_select(const float* __restrict__ mine,
                                               const float* __restrict__ p_ll,
                                               const float* __restrict__ p_lc,
                                               const int* __restrict__ p_np,
                                               float* __restrict__ acc,
                                               int* __restrict__ acc_np,
                                               unsigned* __restrict__ done,
                                               float* __restrict__ out) {
    const int b = blockIdx.x;
    const int tid = threadIdx.x;
    const int wid = tid >> 6, lane = tid & 63;
    constexpr int NW = ST / 64;

    float ll = 0.0f, lc = 0.0f;
    int np = 0;
    for (int i = tid; i < NKB; i += ST) {
        ll += p_ll[b * NKB + i];
        lc += p_lc[b * NKB + i];
        np += p_np[b * NKB + i];
    }
    for (int off = 32; off > 0; off >>= 1) {
        ll += __shfl_down(ll, off, 64);
        lc += __shfl_down(lc, off, 64);
        np += __shfl_down(np, off, 64);
    }
    __shared__ float rll[NW], rlc[NW];
    __shared__ int rnp[NW];
    __shared__ float s_ll, s_lc;
    __shared__ int s_np;
    if (lane == 0) { rll[wid] = ll; rlc[wid] = lc; rnp[wid] = np; }
    __syncthreads();
    if (tid == 0) {
        float a = 0.0f, c = 0.0f;
        int n = 0;
        for (int w = 0; w < NW; ++w) { a += rll[w]; c += rlc[w]; n += rnp[w]; }
        s_ll = a; s_lc = c; s_np = n;
    }
    __syncthreads();
    const int np_b = s_np;
    const int k = min(NEGPOS * np_b, PP - 1);
    float neg = 0.0f;

    const float* mv = mine + (size_t)b * PP;
    if (k > 0) {
        __shared__ unsigned swh[NW * 16];
        __shared__ unsigned stot[16];
        __shared__ unsigned s_prefix;
        __shared__ int s_rem;
        __shared__ float s_neg;
        if (tid == 0) { s_prefix = 0u; s_rem = k; }
        __syncthreads();

        for (int pass = 0; pass < 8; ++pass) {
            const int shift = 28 - 4 * pass;
            const unsigned hm = (pass == 0) ? 0u : (0xFFFFFFFFu << (shift + 4));
            const unsigned prefix = s_prefix;

            unsigned cnt[16];
#pragma unroll
            for (int v = 0; v < 16; ++v) cnt[v] = 0u;

            for (int i = tid; i < PP; i += ST) {
                unsigned bits = __float_as_uint(mv[i]);
                unsigned key = ((bits & hm) == prefix) ? ((bits >> shift) & 15u) : 16u;
                if (__any(key != 16u)) {
#pragma unroll
                    for (int v = 0; v < 16; ++v)
                        cnt[v] += (unsigned)__popcll(__ballot(key == (unsigned)v));
                }
            }
            if (lane == 0) {
#pragma unroll
                for (int v = 0; v < 16; ++v) swh[wid * 16 + v] = cnt[v];
            }
            __syncthreads();
            if (tid < 16) {
                unsigned tt = 0;
#pragma unroll
                for (int w = 0; w < NW; ++w) tt += swh[w * 16 + tid];
                stot[tid] = tt;
            }
            __syncthreads();
            if (tid == 0) {
                int rem = s_rem;
                unsigned cum = 0;
                int chosen = 0;
                for (int v = 15; v >= 0; --v) {
                    unsigned c = stot[v];
                    if (cum + c >= (unsigned)rem) { chosen = v; s_rem = rem - (int)cum; break; }
                    cum += c;
                }
                s_prefix = prefix | ((unsigned)chosen << shift);
            }
            __syncthreads();
        }

        const unsigned T = s_prefix;
        float sum = 0.0f;
        unsigned cnt = 0;
        for (int i = tid; i < PP; i += ST) {
            float v = mv[i];
            if (__float_as_uint(v) > T) { sum += v; cnt++; }
        }
        for (int off = 32; off > 0; off >>= 1) {
            sum += __shfl_down(sum, off, 64);
            cnt += __shfl_down(cnt, off, 64);
        }
        __shared__ float rs[NW];
        __shared__ unsigned rc[NW];
        if (lane == 0) { rs[wid] = sum; rc[wid] = cnt; }
        __syncthreads();
        if (tid == 0) {
            float S = 0.0f;
            int G = 0;
            for (int w = 0; w < NW; ++w) { S += rs[w]; G += (int)rc[w]; }
            s_neg = S + (float)(k - G) * __uint_as_float(T);
        }
        __syncthreads();
        neg = s_neg;
    }

    if (tid == 0) {
        atomicAdd(&acc[0], s_ll);
        atomicAdd(&acc[1], s_lc + neg);
        atomicAdd(acc_np, np_b);
        __threadfence();
        unsigned prev = atomicAdd(done, 1u);
        if (prev == BB - 1) {
            int tp = atomicAdd(acc_np, 0);
            float N = (float)max(tp, 1);
            float a0 = atomicAdd(&acc[0], 0.0f);
            float a1 = atomicAdd(&acc[1], 0.0f);
            out[0] = a0 / N;
            out[1] = a1 / N;
        }
    }
}

extern "C" void kernel_launch(void* const* d_in, const int* in_sizes, int n_in,
                              void* d_out, int out_size, void* d_ws, size_t ws_size,
                              hipStream_t stream) {
    const float* loc    = (const float*)d_in[0];
    const float* conf   = (const float*)d_in[1];
    const float* priors = (const float*)d_in[2];
    const float* gt     = (const float*)d_in[3];
    const int*   labels = (const int*)d_in[4];
    float* out = (float*)d_out;

    char* ws = (char*)d_ws;
    const size_t SZ_BP = (size_t)BB * PP * 4;        // 1,231,872 B
    const size_t SZ_SLOT = (size_t)BB * NKB * 4;     // 4,864 B
    // [0,8) acc | [8,12) acc_np | [12,16) done | [64,4160) gkey | arrays @4224
    float*    acc    = (float*)   (ws);
    int*      acc_np = (int*)     (ws + 8);
    unsigned* done   = (unsigned*)(ws + 12);
    unsigned long long* gkey = (unsigned long long*)(ws + 64);
    float* bto  = (float*)(ws + 4224);
    int*   bti  = (int*)  (ws + 4224 + SZ_BP);
    float* mine = (float*)(ws + 4224 + 2 * SZ_BP);
    float* p_ll = (float*)(ws + 4224 + 3 * SZ_BP);
    float* p_lc = (float*)(ws + 4224 + 3 * SZ_BP + SZ_SLOT);
    int*   p_np = (int*)  (ws + 4224 + 3 * SZ_BP + 2 * SZ_SLOT);

    // zero acc/done AND gkey: atomicMax needs 0-init (harness poisons ws w/ 0xAA)
    (void)hipMemsetAsync(ws, 0, 4224, stream);

    dim3 mg(NMB, BB);
    k_match_prior<<<mg, MTB, 0, stream>>>(priors, gt, bto, bti);

    k_match_gt<<<1024, 256, 0, stream>>>(priors, gt, gkey);   // 4096 waves

    dim3 kg(NKB, BB);
    k_main<<<kg, KTB, 0, stream>>>(loc, conf, priors, gt, labels, bto, bti, gkey,
                                   mine, p_ll, p_lc, p_np);

    k_select<<<BB, ST, 0, stream>>>(mine, p_ll, p_lc, p_np, acc, acc_np, done, out);
}

// Round 10
// 282.602 us; speedup vs baseline: 1.2803x; 1.0070x over previous
//
#include <hip/hip_runtime.h>
#include <cstdint>
#include <cstddef>

#define BB 16
#define PP 19248
#define NOBJ 32
#define NCLS 81
#define POS_TH 0.5f
#define NEG_TH 0.4f
#define VAR0 0.1f
#define VAR1 0.2f
#define NEGPOS 3

#define MTB 256
#define NMB ((PP + MTB - 1) / MTB)      // 76 blocks-x per batch (prior side)
#define GTBLK 1024                       // gt-side blocks (4096 waves)
#define KROWS 32                         // rows per wave in k_main
#define KTB 256                          // 4 waves/block -> 128 rows/block
#define KRB (KTB / 64 * KROWS)           // 128 rows per block
#define NKB ((PP + KRB - 1) / KRB)       // 151
#define ST 1024
#define GTC 2406                         // priors per gt-chunk (8*2406 = 19248)

// ---------------- match (fused): prior-side argmax + gt-side best prior ----------------
__global__ __launch_bounds__(MTB) void k_match(const float* __restrict__ priors,
                                               const float* __restrict__ gt_boxes,
                                               float* __restrict__ bto,
                                               int* __restrict__ bti,
                                               unsigned long long* __restrict__ gkey) {
    const int blk = blockIdx.x;
    if (blk < NMB * BB) {
        // ---- per-prior best gt ----
        const int b = blk / NMB;
        const int p = (blk % NMB) * MTB + threadIdx.x;
        __shared__ float4 sg[NOBJ];
        if (threadIdx.x < NOBJ) sg[threadIdx.x] = ((const float4*)gt_boxes)[b * NOBJ + threadIdx.x];
        __syncthreads();
        if (p >= PP) return;

        float4 pr = ((const float4*)priors)[p];
        float hw = pr.z / 2.0f, hh = pr.w / 2.0f;
        float px1 = pr.x - hw, py1 = pr.y - hh, px2 = pr.x + hw, py2 = pr.y + hh;
        float parea = (px2 - px1) * (py2 - py1);

        float best = -1.0f;
        int bn = 0;
#pragma unroll 4
        for (int n = 0; n < NOBJ; ++n) {
            float4 g = sg[n];
            float iou;
            {
#pragma clang fp contract(off)
                float ix1 = fmaxf(g.x, px1), iy1 = fmaxf(g.y, py1);
                float ix2 = fminf(g.z, px2), iy2 = fminf(g.w, py2);
                float iw = fmaxf(ix2 - ix1, 0.0f), ih = fmaxf(iy2 - iy1, 0.0f);
                float inter = iw * ih;
                float garea = (g.z - g.x) * (g.w - g.y);
                iou = inter / (garea + parea - inter);
            }
            if (iou > best) { best = iou; bn = n; }
        }
        bto[(size_t)b * PP + p] = best;
        bti[(size_t)b * PP + p] = bn;
    } else {
        // ---- per-gt best prior, 8-way chunked, atomicMax merge ----
        const int w = ((blk - NMB * BB) * 256 + threadIdx.x) >> 6;   // 0..4095
        const int b = w >> 8;
        const int rem = w & 255;
        const int n = rem >> 3, chunk = rem & 7;
        const int lane = threadIdx.x & 63;

        const float* g = gt_boxes + (size_t)(b * NOBJ + n) * 4;
        const float gx1 = g[0], gy1 = g[1], gx2 = g[2], gy2 = g[3];
        const float garea = (gx2 - gx1) * (gy2 - gy1);

        const int pbeg = chunk * GTC;
        const int pend = min(pbeg + GTC, PP);

        unsigned long long best = 0ull;
        for (int p = pbeg + lane; p < pend; p += 64) {
            float4 pr = ((const float4*)priors)[p];
            float hw = pr.z / 2.0f, hh = pr.w / 2.0f;
            float px1 = pr.x - hw, py1 = pr.y - hh, px2 = pr.x + hw, py2 = pr.y + hh;
            float parea = (px2 - px1) * (py2 - py1);
            float iou;
            {
#pragma clang fp contract(off)
                float ix1 = fmaxf(gx1, px1), iy1 = fmaxf(gy1, py1);
                float ix2 = fminf(gx2, px2), iy2 = fminf(gy2, py2);
                float iw = fmaxf(ix2 - ix1, 0.0f), ih = fmaxf(iy2 - iy1, 0.0f);
                float inter = iw * ih;
                iou = inter / (garea + parea - inter);
            }
            unsigned long long key = (((unsigned long long)__float_as_uint(iou)) << 32) |
                                     (unsigned long long)(0xFFFFFFFFu - (unsigned)p);
            if (key > best) best = key;
        }
        for (int off = 1; off < 64; off <<= 1) {
            unsigned long long o = __shfl_xor(best, off, 64);
            if (o > best) best = o;
        }
        if (lane == 0) atomicMax(&gkey[b * NOBJ + n], best);
    }
}

__device__ __forceinline__ float sl1(float d) {
    float ad = fabsf(d);
    return ad < 1.0f ? 0.5f * d * d : ad - 0.5f;
}

// ---------------- main: wave-per-row, 32 rows/wave for max TLP, zero atomics ----------------
__global__ __launch_bounds__(KTB) void k_main(const float* __restrict__ loc_data,
                                              const float* __restrict__ conf_data,
                                              const float* __restrict__ priors,
                                              const float* __restrict__ gt_boxes,
                                              const int* __restrict__ gt_labels,
                                              const float* __restrict__ bto,
                                              const int* __restrict__ bti,
                                              const unsigned long long* __restrict__ gkey,
                                              float* __restrict__ mine,
                                              float* __restrict__ p_ll,
                                              float* __restrict__ p_lc,
                                              int* __restrict__ p_np) {
    const int b = blockIdx.y;
    const int tid = threadIdx.x;
    const int wid = tid >> 6, lane = tid & 63;
    const int base = blockIdx.x * KRB + wid * KROWS;
    const int nrows = min(KROWS, PP - base);

    unsigned pstar = 0xFFFFFFFFu;
    int lab = 0;
    if (lane < NOBJ) {
        unsigned long long key = gkey[b * NOBJ + lane];
        pstar = 0xFFFFFFFFu - (unsigned)(key & 0xFFFFFFFFull);
        lab = gt_labels[b * NOBJ + lane];
    }

    float a_ll = 0.0f, a_lc = 0.0f;
    int a_np = 0;
    float mval = 0.0f;

    if (nrows > 0) {
        const float* row0 = conf_data + ((size_t)b * PP + base) * NCLS;

#pragma unroll 2
        for (int j = 0; j < nrows; ++j) {
            const int r = base + j;
            const float* rp = row0 + (size_t)j * NCLS;
            float v1 = rp[lane];
            float v2 = (lane < NCLS - 64) ? rp[64 + lane] : -1e30f;

            float e = __expf(v1) + __expf(v2);
            e += __shfl_xor(e, 1, 64);
            e += __shfl_xor(e, 2, 64);
            e += __shfl_xor(e, 4, 64);
            e += __shfl_xor(e, 8, 64);
            e += __shfl_xor(e, 16, 64);
            e += __shfl_xor(e, 32, 64);
            const float lse = __logf(e);

            float ov = bto[(size_t)b * PP + r];   // wave-uniform address -> scalarized
            int ti = bti[(size_t)b * PP + r];
            unsigned long long ball = __ballot(pstar == (unsigned)r);
            if (ball) {
                ti = 63 - __builtin_clzll(ball);   // last n wins
                ov = 2.0f;
            }
            int conf_c = __shfl(lab, ti, 64) + 1;
            if (ov < POS_TH) conf_c = -1;
            if (ov < NEG_TH) conf_c = 0;
            const int ct = conf_c > 0 ? conf_c : 0;
            float vct;
            if (ct == 0) {   // wave-uniform branch: ~97% of rows skip the DS op
                vct = __uint_as_float(__builtin_amdgcn_readfirstlane(__float_as_uint(v1)));
            } else if (ct < 64) {
                vct = __shfl(v1, ct, 64);
            } else {
                vct = __shfl(v2, ct - 64, 64);
            }
            const float nll = lse - vct;

            if (conf_c > 0) {   // wave-uniform, rare
                float4 gbox = ((const float4*)gt_boxes)[b * NOBJ + ti];
                float4 pr = ((const float4*)priors)[r];
                float mcx = (gbox.x + gbox.z) / 2.0f, mcy = (gbox.y + gbox.w) / 2.0f;
                float mw = gbox.z - gbox.x, mh = gbox.w - gbox.y;
                float t0 = (mcx - pr.x) / (VAR0 * pr.z);
                float t1 = (mcy - pr.y) / (VAR0 * pr.w);
                float t2 = logf(mw / pr.z) / VAR1;
                float t3 = logf(mh / pr.w) / VAR1;
                float4 ld = ((const float4*)loc_data)[(size_t)b * PP + r];
                a_ll += sl1(ld.x - t0) + sl1(ld.y - t1) + sl1(ld.z - t2) + sl1(ld.w - t3);
                a_lc += nll;
                a_np += 1;
            }
            mval = (lane == j) ? ((conf_c == 0) ? nll : 0.0f) : mval;
        }
        if (lane < nrows) mine[(size_t)b * PP + base + lane] = mval;   // coalesced
    }

    __shared__ float sll[4], slc[4];
    __shared__ int snp[4];
    if (lane == 0) { sll[wid] = a_ll; slc[wid] = a_lc; snp[wid] = a_np; }
    __syncthreads();
    if (tid == 0) {
        p_ll[b * NKB + blockIdx.x] = sll[0] + sll[1] + sll[2] + sll[3];
        p_lc[b * NKB + blockIdx.x] = slc[0] + slc[1] + slc[2] + slc[3];
        p_np[b * NKB + blockIdx.x] = snp[0] + snp[1] + snp[2] + snp[3];
    }
}

// ---------------- select: partial-slot reduce + ballot radix top-k + fused finalize ----------------
__global__ __launch_bounds__(ST) void k_select(const float* __restrict__ mine,
                                               const float* __restrict__ p_ll,
                                               const float* __restrict__ p_lc,
                                               const int* __restrict__ p_np,
                                               float* __restrict__ acc,
                                               int* __restrict__ acc_np,
                                               unsigned* __restrict__ done,
                                               float* __restrict__ out) {
    const int b = blockIdx.x;
    const int tid = threadIdx.x;
    const int wid = tid >> 6, lane = tid & 63;
    constexpr int NW = ST / 64;

    float ll = 0.0f, lc = 0.0f;
    int np = 0;
    for (int i = tid; i < NKB; i += ST) {
        ll += p_ll[b * NKB + i];
        lc += p_lc[b * NKB + i];
        np += p_np[b * NKB + i];
    }
    for (int off = 32; off > 0; off >>= 1) {
        ll += __shfl_down(ll, off, 64);
        lc += __shfl_down(lc, off, 64);
        np += __shfl_down(np, off, 64);
    }
    __shared__ float rll[NW], rlc[NW];
    __shared__ int rnp[NW];
    __shared__ float s_ll, s_lc;
    __shared__ int s_np;
    if (lane == 0) { rll[wid] = ll; rlc[wid] = lc; rnp[wid] = np; }
    __syncthreads();
    if (tid == 0) {
        float a = 0.0f, c = 0.0f;
        int n = 0;
        for (int w = 0; w < NW; ++w) { a += rll[w]; c += rlc[w]; n += rnp[w]; }
        s_ll = a; s_lc = c; s_np = n;
    }
    __syncthreads();
    const int np_b = s_np;
    const int k = min(NEGPOS * np_b, PP - 1);
    float neg = 0.0f;

    const float* mv = mine + (size_t)b * PP;
    if (k > 0) {
        __shared__ unsigned swh[NW * 16];
        __shared__ unsigned stot[16];
        __shared__ unsigned s_prefix;
        __shared__ int s_rem;
        __shared__ float s_neg;
        if (tid == 0) { s_prefix = 0u; s_rem = k; }
        __syncthreads();

        for (int pass = 0; pass < 8; ++pass) {
            const int shift = 28 - 4 * pass;
            const unsigned hm = (pass == 0) ? 0u : (0xFFFFFFFFu << (shift + 4));
            const unsigned prefix = s_prefix;

            unsigned cnt[16];
#pragma unroll
            for (int v = 0; v < 16; ++v) cnt[v] = 0u;

            for (int i = tid; i < PP; i += ST) {
                unsigned bits = __float_as_uint(mv[i]);
                unsigned key = ((bits & hm) == prefix) ? ((bits >> shift) & 15u) : 16u;
                if (__any(key != 16u)) {
#pragma unroll
                    for (int v = 0; v < 16; ++v)
                        cnt[v] += (unsigned)__popcll(__ballot(key == (unsigned)v));
                }
            }
            if (lane == 0) {
#pragma unroll
                for (int v = 0; v < 16; ++v) swh[wid * 16 + v] = cnt[v];
            }
            __syncthreads();
            if (tid < 16) {
                unsigned tt = 0;
#pragma unroll
                for (int w = 0; w < NW; ++w) tt += swh[w * 16 + tid];
                stot[tid] = tt;
            }
            __syncthreads();
            if (tid == 0) {
                int rem = s_rem;
                unsigned cum = 0;
                int chosen = 0;
                for (int v = 15; v >= 0; --v) {
                    unsigned c = stot[v];
                    if (cum + c >= (unsigned)rem) { chosen = v; s_rem = rem - (int)cum; break; }
                    cum += c;
                }
                s_prefix = prefix | ((unsigned)chosen << shift);
            }
            __syncthreads();
        }

        const unsigned T = s_prefix;
        float sum = 0.0f;
        unsigned cnt = 0;
        for (int i = tid; i < PP; i += ST) {
            float v = mv[i];
            if (__float_as_uint(v) > T) { sum += v; cnt++; }
        }
        for (int off = 32; off > 0; off >>= 1) {
            sum += __shfl_down(sum, off, 64);
            cnt += __shfl_down(cnt, off, 64);
        }
        __shared__ float rs[NW];
        __shared__ unsigned rc[NW];
        if (lane == 0) { rs[wid] = sum; rc[wid] = cnt; }
        __syncthreads();
        if (tid == 0) {
            float S = 0.0f;
            int G = 0;
            for (int w = 0; w < NW; ++w) { S += rs[w]; G += (int)rc[w]; }
            s_neg = S + (float)(k - G) * __uint_as_float(T);
        }
        __syncthreads();
        neg = s_neg;
    }

    if (tid == 0) {
        atomicAdd(&acc[0], s_ll);
        atomicAdd(&acc[1], s_lc + neg);
        atomicAdd(acc_np, np_b);
        __threadfence();
        unsigned prev = atomicAdd(done, 1u);
        if (prev == BB - 1) {
            int tp = atomicAdd(acc_np, 0);
            float N = (float)max(tp, 1);
            float a0 = atomicAdd(&acc[0], 0.0f);
            float a1 = atomicAdd(&acc[1], 0.0f);
            out[0] = a0 / N;
            out[1] = a1 / N;
        }
    }
}

extern "C" void kernel_launch(void* const* d_in, const int* in_sizes, int n_in,
                              void* d_out, int out_size, void* d_ws, size_t ws_size,
                              hipStream_t stream) {
    const float* loc    = (const float*)d_in[0];
    const float* conf   = (const float*)d_in[1];
    const float* priors = (const float*)d_in[2];
    const float* gt     = (const float*)d_in[3];
    const int*   labels = (const int*)d_in[4];
    float* out = (float*)d_out;

    char* ws = (char*)d_ws;
    const size_t SZ_BP = (size_t)BB * PP * 4;        // 1,231,872 B
    const size_t SZ_SLOT = (size_t)BB * NKB * 4;     // 9,664 B
    // [0,8) acc | [8,12) acc_np | [12,16) done | [64,4160) gkey | arrays @4224
    float*    acc    = (float*)   (ws);
    int*      acc_np = (int*)     (ws + 8);
    unsigned* done   = (unsigned*)(ws + 12);
    unsigned long long* gkey = (unsigned long long*)(ws + 64);
    float* bto  = (float*)(ws + 4224);
    int*   bti  = (int*)  (ws + 4224 + SZ_BP);
    float* mine = (float*)(ws + 4224 + 2 * SZ_BP);
    float* p_ll = (float*)(ws + 4224 + 3 * SZ_BP);
    float* p_lc = (float*)(ws + 4224 + 3 * SZ_BP + SZ_SLOT);
    int*   p_np = (int*)  (ws + 4224 + 3 * SZ_BP + 2 * SZ_SLOT);

    // zero acc/done AND gkey (atomicMax needs 0-init; harness poisons ws w/ 0xAA)
    (void)hipMemsetAsync(ws, 0, 4224, stream);

    k_match<<<NMB * BB + GTBLK, MTB, 0, stream>>>(priors, gt, bto, bti, gkey);

    dim3 kg(NKB, BB);
    k_main<<<kg, KTB, 0, stream>>>(loc, conf, priors, gt, labels, bto, bti, gkey,
                                   mine, p_ll, p_lc, p_np);

    k_select<<<BB, ST, 0, stream>>>(mine, p_ll, p_lc, p_np, acc, acc_np, done, out);
}